// Round 1
// baseline (247.306 us; speedup 1.0000x reference)
//
#include <hip/hip_runtime.h>
#include <hip/hip_bf16.h>

#define NOBJ 21

typedef __bf16 bf16x8 __attribute__((ext_vector_type(8)));
typedef float f32x16 __attribute__((ext_vector_type(16)));

__device__ __forceinline__ float ftanh(float x) {
    // tanh(x) = sign(x) * (1 - 2/(exp(2|x|)+1)) ; exact identity, ~1e-7 abs err
    float ax = fminf(fabsf(x), 15.0f);
    float e  = __expf(2.0f * ax);
    float r  = 1.0f - 2.0f / (e + 1.0f);
    return copysignf(r, x);
}

// fe3[c][e] = tanh( tanh(emb[c]) @ We + be )[e]   (only 3 categories exist)
__global__ void setup_kernel(const float* __restrict__ emb, const float* __restrict__ We,
                             const float* __restrict__ be, float* __restrict__ fe3) {
    int t = threadIdx.x;
    if (t < 192) {
        int c = t >> 6, e = t & 63;
        float acc = be[e];
        for (int k = 0; k < 64; ++k)
            acc += ftanh(emb[c * 64 + k]) * We[k * 64 + e];
        fe3[t] = ftanh(acc);
    }
}

// LDS byte offsets (overlaid regions)
#define OFF_U   0        // float u[21][128]      10752
#define OFF_V   10752    // float v[21][128]      10752
#define OFF_X   21504    // float x[21][128]      10752
#define OFF_A   32256    // regionA (40960):
                         //   phase2: bf16 W2T[128][128] (32768) + bf16 T[32][128] (8192)
                         //   phase1: float h[21][128] (10752) @ +0, float f[21][192] (16128) @ +10752
                         //   phase3: float a1[21][128] (10752) @ +0
#define OFF_T   65024
#define OFF_SPL 73216    // float spl[21][4]
#define OFF_CAT 73552    // int   cat[21]
#define SMEM_SZ 73648

__global__ __launch_bounds__(256, 2)
void actor_kernel(const float* __restrict__ state, const float* __restrict__ ts,
                  const float* __restrict__ Ws1, const float* __restrict__ bs1,
                  const float* __restrict__ Ws2, const float* __restrict__ bs2,
                  const float* __restrict__ Wm1, const float* __restrict__ bm1,
                  const float* __restrict__ Wm2, const float* __restrict__ bm2,
                  const float* __restrict__ Wa1, const float* __restrict__ ba1,
                  const float* __restrict__ Wa2, const float* __restrict__ ba2,
                  const float* __restrict__ fe3, float* __restrict__ out) {
    __shared__ __align__(16) unsigned char smem[SMEM_SZ];
    float*  uL  = (float*)(smem + OFF_U);
    float*  vL  = (float*)(smem + OFF_V);
    float*  xL  = (float*)(smem + OFF_X);
    __bf16* W2T = (__bf16*)(smem + OFF_A);
    __bf16* T   = (__bf16*)(smem + OFF_T);
    float*  hL  = (float*)(smem + OFF_A);
    float*  fL  = (float*)(smem + OFF_A + 10752);
    float*  a1L = (float*)(smem + OFF_A);
    float*  spl = (float*)(smem + OFF_SPL);
    int*    catl= (int*)(smem + OFF_CAT);

    const int b   = blockIdx.x;
    const int tid = threadIdx.x;
    const int c   = tid & 127;
    const int half= tid >> 7;
    const int i0  = half ? 11 : 0;
    const int i1  = half ? NOBJ : 11;
    const int NI  = i1 - i0;   // 11 or 10

    // ---- step 0: per-object scalars ----
    if (tid < NOBJ * 4) {
        int i = tid >> 2, m = tid & 3;
        float v;
        if (m < 2) v = state[b * 63 + i * 3 + m];
        else       v = ftanh(ts[(b * NOBJ + i) * 2 + (m - 2)]);
        spl[tid] = v;
    }
    if (tid >= 128 && tid < 128 + NOBJ) {
        int i = tid - 128;
        catl[i] = (int)state[b * 63 + i * 3 + 2];
    }
    __syncthreads();

    // ---- step 1: h = tanh(sp @ Ws1 + bs1) ----
    {
        float b1 = bs1[c];
        float w0 = Ws1[0 * 128 + c], w1 = Ws1[1 * 128 + c];
        float w2 = Ws1[2 * 128 + c], w3 = Ws1[3 * 128 + c];
        for (int i = i0; i < i1; ++i) {
            float acc = b1 + spl[i*4+0]*w0 + spl[i*4+1]*w1 + spl[i*4+2]*w2 + spl[i*4+3]*w3;
            hL[i * 128 + c] = ftanh(acc);
        }
    }
    __syncthreads();

    // ---- step 2: f[:, :128] = tanh(h @ Ws2 + bs2) ; f[:,128:] = fe3[cat] ----
    {
        float acc[11];
        #pragma unroll
        for (int g = 0; g < 11; ++g) acc[g] = 0.f;
        for (int k = 0; k < 128; ++k) {
            float w = Ws2[k * 128 + c];
            #pragma unroll
            for (int g = 0; g < 11; ++g)
                if (g < NI) acc[g] += hL[(i0 + g) * 128 + k] * w;
        }
        float b2 = bs2[c];
        for (int g = 0; g < NI; ++g)
            fL[(i0 + g) * 192 + c] = ftanh(acc[g] + b2);
    }
    for (int idx = tid; idx < NOBJ * 64; idx += 256) {
        int i = idx >> 6, e = idx & 63;
        fL[i * 192 + 128 + e] = fe3[catl[i] * 64 + e];
    }
    __syncthreads();

    // ---- step 3: u = f@(Wm1_top - Wm1_bot) + bm1 ; v = f@Wm1_bot ----
    {
        float ua[11], va[11];
        #pragma unroll
        for (int g = 0; g < 11; ++g) { ua[g] = 0.f; va[g] = 0.f; }
        for (int k = 0; k < 192; ++k) {
            float wt = Wm1[k * 128 + c];
            float wb = Wm1[(192 + k) * 128 + c];
            float wd = wt - wb;
            #pragma unroll
            for (int g = 0; g < 11; ++g) {
                if (g < NI) {
                    float fv = fL[(i0 + g) * 192 + k];
                    ua[g] += fv * wd;
                    va[g] += fv * wb;
                }
            }
        }
        float b1 = bm1[c];
        for (int g = 0; g < NI; ++g) {
            uL[(i0 + g) * 128 + c] = ua[g] + b1;
            vL[(i0 + g) * 128 + c] = va[g];
        }
    }
    __syncthreads();

    // ---- load Wm2 -> W2T bf16 [c][k], chunk-XOR swizzled; zero T pad rows ----
    for (int idx = tid; idx < 128 * 128; idx += 256) {
        int k = idx >> 7, cc = idx & 127;
        int ch = k >> 3;
        W2T[cc * 128 + ((ch ^ (cc & 15)) << 3) + (k & 7)] = (__bf16)Wm2[idx];
    }
    for (int idx = NOBJ * 128 + tid; idx < 32 * 128; idx += 256)
        T[idx] = (__bf16)0.f;
    __syncthreads();

    // ---- phase 2: per i, msg = tanh(u_i + v_j) @ Wm2 ; x = tanh(max_j + bm2) ----
    const int lane = tid & 63;
    const int wave = tid >> 6;
    const int rowA = lane & 31;
    const int hi   = lane >> 5;
    const int cN   = wave * 32 + rowA;     // output column for this lane
    const float bm2c = bm2[cN];

    for (int i = 0; i < NOBJ; ++i) {
        // build T[j][k] = bf16(tanh(u_i[k] + v_j[k])), swizzled 16B chunks
        for (int q = tid; q < NOBJ * 16; q += 256) {
            int j = q >> 4, ch = q & 15;
            int k0 = ch << 3;
            bf16x8 pv;
            #pragma unroll
            for (int e = 0; e < 8; ++e)
                pv[e] = (__bf16)ftanh(uL[i * 128 + k0 + e] + vL[j * 128 + k0 + e]);
            *reinterpret_cast<bf16x8*>(&T[j * 128 + ((ch ^ (j & 15)) << 3)]) = pv;
        }
        __syncthreads();

        f32x16 acc;
        #pragma unroll
        for (int r = 0; r < 16; ++r) acc[r] = 0.f;
        #pragma unroll
        for (int ks = 0; ks < 8; ++ks) {
            int chA = ks * 2 + hi;
            bf16x8 a  = *reinterpret_cast<const bf16x8*>(&T[rowA * 128 + ((chA ^ (rowA & 15)) << 3)]);
            bf16x8 bb = *reinterpret_cast<const bf16x8*>(&W2T[cN * 128 + ((chA ^ (cN & 15)) << 3)]);
            acc = __builtin_amdgcn_mfma_f32_32x32x16_bf16(a, bb, acc, 0, 0, 0);
        }
        // D layout: col = lane&31, row = (reg&3) + 8*(reg>>2) + 4*(lane>>5)
        float m = -INFINITY;
        #pragma unroll
        for (int r = 0; r < 16; ++r) {
            int rowj = (r & 3) + 8 * (r >> 2) + 4 * hi;
            if (rowj < NOBJ && rowj != i) m = fmaxf(m, acc[r]);
        }
        m = fmaxf(m, __shfl_xor(m, 32));
        if (hi == 0) xL[i * 128 + cN] = ftanh(m + bm2c);
        __syncthreads();
    }

    // ---- phase 3: a1 = tanh(x @ Wa1 + ba1) ----
    {
        float acc[11];
        #pragma unroll
        for (int g = 0; g < 11; ++g) acc[g] = 0.f;
        for (int k = 0; k < 128; ++k) {
            float w = Wa1[k * 128 + c];
            #pragma unroll
            for (int g = 0; g < 11; ++g)
                if (g < NI) acc[g] += xL[(i0 + g) * 128 + k] * w;
        }
        float b1 = ba1[c];
        for (int g = 0; g < NI; ++g)
            a1L[(i0 + g) * 128 + c] = ftanh(acc[g] + b1);
    }
    __syncthreads();

    // ---- act = a1 @ Wa2 + ba2 ; outputs ----
    if (tid < NOBJ * 4) {
        int i = tid >> 2, o = tid & 3;
        float acc = ba2[o];
        for (int k = 0; k < 128; ++k) acc += a1L[i * 128 + k] * Wa2[k * 4 + o];
        if (o < 2) {
            out[b * 42 + i * 2 + o] = 0.3f * ftanh(acc);
        } else {
            float t   = ftanh(acc);
            float lsv = -5.0f + 3.5f * (t + 1.0f);
            out[43008 + b * 42 + i * 2 + (o - 2)] = expf(lsv);
        }
    }
}

extern "C" void kernel_launch(void* const* d_in, const int* in_sizes, int n_in,
                              void* d_out, int out_size, void* d_ws, size_t ws_size,
                              hipStream_t stream) {
    (void)in_sizes; (void)n_in; (void)out_size; (void)ws_size;
    const float* state = (const float*)d_in[0];
    const float* ts    = (const float*)d_in[1];
    const float* emb   = (const float*)d_in[2];
    const float* We    = (const float*)d_in[3];
    const float* be    = (const float*)d_in[4];
    const float* Ws1   = (const float*)d_in[5];
    const float* bs1   = (const float*)d_in[6];
    const float* Ws2   = (const float*)d_in[7];
    const float* bs2   = (const float*)d_in[8];
    const float* Wm1   = (const float*)d_in[9];
    const float* bm1   = (const float*)d_in[10];
    const float* Wm2   = (const float*)d_in[11];
    const float* bm2   = (const float*)d_in[12];
    const float* Wa1   = (const float*)d_in[13];
    const float* ba1   = (const float*)d_in[14];
    const float* Wa2   = (const float*)d_in[15];
    const float* ba2   = (const float*)d_in[16];
    float* outp = (float*)d_out;
    float* fe3  = (float*)d_ws;

    setup_kernel<<<dim3(1), dim3(192), 0, stream>>>(emb, We, be, fe3);
    actor_kernel<<<dim3(1024), dim3(256), 0, stream>>>(
        state, ts, Ws1, bs1, Ws2, bs2, Wm1, bm1, Wm2, bm2,
        Wa1, ba1, Wa2, ba2, fe3, outp);
}

// Round 2
// 205.315 us; speedup vs baseline: 1.2045x; 1.2045x over previous
//
#include <hip/hip_runtime.h>
#include <hip/hip_bf16.h>

#define NOBJ 21

typedef __bf16 bf16x8 __attribute__((ext_vector_type(8)));
typedef float f32x16 __attribute__((ext_vector_type(16)));
typedef float f32x4  __attribute__((ext_vector_type(4)));

__device__ __forceinline__ float ftanh(float x) {
    // tanh(x) = 1 - 2/(exp(2x)+1), branchless. Saturates exactly: exp->inf => rcp->0 => 1;
    // exp->0 => rcp(1)=1 => -1. v_exp/v_rcp approx err ~1e-7, irrelevant vs bf16.
    float e = __expf(2.0f * x);
    float r = __builtin_amdgcn_rcpf(e + 1.0f);
    return __builtin_fmaf(-2.0f, r, 1.0f);
}

// fe3[c][e] = tanh( tanh(emb[c]) @ We + be )[e]   (only 3 categories exist)
__global__ void setup_kernel(const float* __restrict__ emb, const float* __restrict__ We,
                             const float* __restrict__ be, float* __restrict__ fe3) {
    int t = threadIdx.x;
    if (t < 192) {
        int c = t >> 6, e = t & 63;
        float acc = be[e];
        for (int k = 0; k < 64; ++k)
            acc += ftanh(emb[c * 64 + k]) * We[k * 64 + e];
        fe3[t] = ftanh(acc);
    }
}

// LDS byte offsets (overlaid regions)
#define OFF_U   0        // float u[21][128]  10752
#define OFF_V   10752    // float v[21][128]  10752
#define OFF_X   21504    // float x[21][128]  10752
#define OFF_A   32256    // regionA (32768):
                         //   phase1: float h[21][128] @ +0, float f[21][192] @ +10752 (ends 26880)
                         //   phase2: bf16 W2T[128][128] (32768)
                         //   phase3: float a1[21][128] @ +0
#define OFF_SPL 65024    // float spl[21][4]   336
#define OFF_CAT 65360    // int   cat[21]      84
#define SMEM_SZ 65472

__global__ __launch_bounds__(256, 2)
void actor_kernel(const float* __restrict__ state, const float* __restrict__ ts,
                  const float* __restrict__ Ws1, const float* __restrict__ bs1,
                  const float* __restrict__ Ws2, const float* __restrict__ bs2,
                  const float* __restrict__ Wm1, const float* __restrict__ bm1,
                  const float* __restrict__ Wm2, const float* __restrict__ bm2,
                  const float* __restrict__ Wa1, const float* __restrict__ ba1,
                  const float* __restrict__ Wa2, const float* __restrict__ ba2,
                  const float* __restrict__ fe3, float* __restrict__ out) {
    __shared__ __align__(16) unsigned char smem[SMEM_SZ];
    float*  uL  = (float*)(smem + OFF_U);
    float*  vL  = (float*)(smem + OFF_V);
    float*  xL  = (float*)(smem + OFF_X);
    __bf16* W2T = (__bf16*)(smem + OFF_A);
    float*  hL  = (float*)(smem + OFF_A);
    float*  fL  = (float*)(smem + OFF_A + 10752);
    float*  a1L = (float*)(smem + OFF_A);
    float*  spl = (float*)(smem + OFF_SPL);
    int*    catl= (int*)(smem + OFF_CAT);

    const int b   = blockIdx.x;
    const int tid = threadIdx.x;
    const int c   = tid & 127;
    const int half= tid >> 7;
    const int i0  = half ? 11 : 0;
    const int i1  = half ? NOBJ : 11;
    const int NI  = i1 - i0;   // 11 or 10

    // ---- step 0: per-object scalars ----
    if (tid < NOBJ * 4) {
        int i = tid >> 2, m = tid & 3;
        float v;
        if (m < 2) v = state[b * 63 + i * 3 + m];
        else       v = ftanh(ts[(b * NOBJ + i) * 2 + (m - 2)]);
        spl[tid] = v;
    }
    if (tid >= 128 && tid < 128 + NOBJ) {
        int i = tid - 128;
        catl[i] = (int)state[b * 63 + i * 3 + 2];
    }
    __syncthreads();

    // ---- step 1: h = tanh(sp @ Ws1 + bs1) ----
    {
        float b1 = bs1[c];
        float w0 = Ws1[0 * 128 + c], w1 = Ws1[1 * 128 + c];
        float w2 = Ws1[2 * 128 + c], w3 = Ws1[3 * 128 + c];
        for (int i = i0; i < i1; ++i) {
            float acc = b1 + spl[i*4+0]*w0 + spl[i*4+1]*w1 + spl[i*4+2]*w2 + spl[i*4+3]*w3;
            hL[i * 128 + c] = ftanh(acc);
        }
    }
    __syncthreads();

    // ---- step 2: f[:, :128] = tanh(h @ Ws2 + bs2) ; f[:,128:] = fe3[cat] ----
    {
        float acc[11];
        #pragma unroll
        for (int g = 0; g < 11; ++g) acc[g] = 0.f;
        for (int k = 0; k < 128; ++k) {
            float w = Ws2[k * 128 + c];
            #pragma unroll
            for (int g = 0; g < 11; ++g)
                if (g < NI) acc[g] += hL[(i0 + g) * 128 + k] * w;
        }
        float b2 = bs2[c];
        for (int g = 0; g < NI; ++g)
            fL[(i0 + g) * 192 + c] = ftanh(acc[g] + b2);
    }
    for (int idx = tid; idx < NOBJ * 64; idx += 256) {
        int i = idx >> 6, e = idx & 63;
        fL[i * 192 + 128 + e] = fe3[catl[i] * 64 + e];
    }
    __syncthreads();

    // ---- step 3: u = f@(Wm1_top - Wm1_bot) + bm1 ; v = f@Wm1_bot ----
    {
        float ua[11], va[11];
        #pragma unroll
        for (int g = 0; g < 11; ++g) { ua[g] = 0.f; va[g] = 0.f; }
        for (int k = 0; k < 192; ++k) {
            float wt = Wm1[k * 128 + c];
            float wb = Wm1[(192 + k) * 128 + c];
            float wd = wt - wb;
            #pragma unroll
            for (int g = 0; g < 11; ++g) {
                if (g < NI) {
                    float fv = fL[(i0 + g) * 192 + k];
                    ua[g] += fv * wd;
                    va[g] += fv * wb;
                }
            }
        }
        float b1 = bm1[c];
        for (int g = 0; g < NI; ++g) {
            uL[(i0 + g) * 128 + c] = ua[g] + b1;
            vL[(i0 + g) * 128 + c] = va[g];
        }
    }
    __syncthreads();

    // ---- stage Wm2 -> W2T bf16 [col][k], chunk-XOR swizzled (overlays dead h/f) ----
    for (int idx = tid; idx < 128 * 128; idx += 256) {
        int k = idx >> 7, cc = idx & 127;
        int ch = k >> 3;
        W2T[cc * 128 + ((ch ^ (cc & 15)) << 3) + (k & 7)] = (__bf16)Wm2[idx];
    }

    const int lane = tid & 63;
    const int wave = tid >> 6;
    const int rowA = lane & 31;              // A-row j; also output col offset
    const int hi   = lane >> 5;
    const int jc   = rowA < NOBJ ? rowA : NOBJ - 1;  // clamp pad rows (masked later)

    // cache this lane's v half-row: v[jc][ks*16 + hi*8 + e]  (64 floats, in VGPRs)
    float vreg[64];
    #pragma unroll
    for (int ks = 0; ks < 8; ++ks) {
        f32x4 p0 = *(const f32x4*)&vL[jc * 128 + ks * 16 + hi * 8];
        f32x4 p1 = *(const f32x4*)&vL[jc * 128 + ks * 16 + hi * 8 + 4];
        #pragma unroll
        for (int e = 0; e < 4; ++e) { vreg[ks*8 + e] = p0[e]; vreg[ks*8 + 4 + e] = p1[e]; }
    }
    float bm2v[4];
    #pragma unroll
    for (int ct = 0; ct < 4; ++ct) bm2v[ct] = bm2[ct * 32 + rowA];
    __syncthreads();   // W2T visible

    // ---- phase 2 (barrier-free): per wave-owned i: x[i,:] = tanh(max_j tanh(u_i+v_j)@Wm2 + bm2)
    for (int i = wave; i < NOBJ; i += 4) {
        bf16x8 afr[8];
        #pragma unroll
        for (int ks = 0; ks < 8; ++ks) {
            f32x4 u0 = *(const f32x4*)&uL[i * 128 + ks * 16 + hi * 8];
            f32x4 u1 = *(const f32x4*)&uL[i * 128 + ks * 16 + hi * 8 + 4];
            bf16x8 a;
            #pragma unroll
            for (int e = 0; e < 4; ++e) a[e]     = (__bf16)ftanh(u0[e] + vreg[ks*8 + e]);
            #pragma unroll
            for (int e = 0; e < 4; ++e) a[4 + e] = (__bf16)ftanh(u1[e] + vreg[ks*8 + 4 + e]);
            afr[ks] = a;
        }
        #pragma unroll
        for (int ct = 0; ct < 4; ++ct) {
            const int cN = ct * 32 + rowA;
            f32x16 acc;
            #pragma unroll
            for (int r = 0; r < 16; ++r) acc[r] = 0.f;
            #pragma unroll
            for (int ks = 0; ks < 8; ++ks) {
                int chA = ks * 2 + hi;
                bf16x8 bb = *(const bf16x8*)&W2T[cN * 128 + ((chA ^ (cN & 15)) << 3)];
                acc = __builtin_amdgcn_mfma_f32_32x32x16_bf16(afr[ks], bb, acc, 0, 0, 0);
            }
            // D layout: col = lane&31, row j = (r&3) + 8*(r>>2) + 4*hi
            float m = -INFINITY;
            #pragma unroll
            for (int r = 0; r < 16; ++r) {
                int rowj = (r & 3) + 8 * (r >> 2) + 4 * hi;
                if (rowj < NOBJ) { if (rowj != i) m = fmaxf(m, acc[r]); }
            }
            m = fmaxf(m, __shfl_xor(m, 32));
            if (hi == 0) xL[i * 128 + cN] = ftanh(m + bm2v[ct]);
        }
    }
    __syncthreads();

    // ---- phase 3: a1 = tanh(x @ Wa1 + ba1)  (a1 overlays dead W2T) ----
    {
        float acc[11];
        #pragma unroll
        for (int g = 0; g < 11; ++g) acc[g] = 0.f;
        for (int k = 0; k < 128; ++k) {
            float w = Wa1[k * 128 + c];
            #pragma unroll
            for (int g = 0; g < 11; ++g)
                if (g < NI) acc[g] += xL[(i0 + g) * 128 + k] * w;
        }
        float b1 = ba1[c];
        for (int g = 0; g < NI; ++g)
            a1L[(i0 + g) * 128 + c] = ftanh(acc[g] + b1);
    }
    __syncthreads();

    // ---- act = a1 @ Wa2 + ba2 ; outputs ----
    if (tid < NOBJ * 4) {
        int i = tid >> 2, o = tid & 3;
        float acc = ba2[o];
        for (int k = 0; k < 128; ++k) acc += a1L[i * 128 + k] * Wa2[k * 4 + o];
        if (o < 2) {
            out[b * 42 + i * 2 + o] = 0.3f * ftanh(acc);
        } else {
            float t   = ftanh(acc);
            float lsv = -5.0f + 3.5f * (t + 1.0f);
            out[43008 + b * 42 + i * 2 + (o - 2)] = expf(lsv);
        }
    }
}

extern "C" void kernel_launch(void* const* d_in, const int* in_sizes, int n_in,
                              void* d_out, int out_size, void* d_ws, size_t ws_size,
                              hipStream_t stream) {
    (void)in_sizes; (void)n_in; (void)out_size; (void)ws_size;
    const float* state = (const float*)d_in[0];
    const float* ts    = (const float*)d_in[1];
    const float* emb   = (const float*)d_in[2];
    const float* We    = (const float*)d_in[3];
    const float* be    = (const float*)d_in[4];
    const float* Ws1   = (const float*)d_in[5];
    const float* bs1   = (const float*)d_in[6];
    const float* Ws2   = (const float*)d_in[7];
    const float* bs2   = (const float*)d_in[8];
    const float* Wm1   = (const float*)d_in[9];
    const float* bm1   = (const float*)d_in[10];
    const float* Wm2   = (const float*)d_in[11];
    const float* bm2   = (const float*)d_in[12];
    const float* Wa1   = (const float*)d_in[13];
    const float* ba1   = (const float*)d_in[14];
    const float* Wa2   = (const float*)d_in[15];
    const float* ba2   = (const float*)d_in[16];
    float* outp = (float*)d_out;
    float* fe3  = (float*)d_ws;

    setup_kernel<<<dim3(1), dim3(192), 0, stream>>>(emb, We, be, fe3);
    actor_kernel<<<dim3(1024), dim3(256), 0, stream>>>(
        state, ts, Ws1, bs1, Ws2, bs2, Wm1, bm1, Wm2, bm2,
        Wa1, ba1, Wa2, ba2, fe3, outp);
}